// Round 1
// 166.661 us; speedup vs baseline: 1.0866x; 1.0866x over previous
//
#include <hip/hip_runtime.h>
#include <math.h>

// Problem constants (from reference)
constexpr int B_ = 16, T_ = 256, D_ = 384, M_ = 2048, F_ = 256, NMEL_ = 80;
constexpr float PACE_ = 1.0f, MAXDUR_ = 75.0f;
constexpr int R_ = B_ * T_;  // 4096 total rows

typedef __attribute__((ext_vector_type(8))) short bf16x8;
typedef __attribute__((ext_vector_type(4))) float f32x4_;

static __device__ __forceinline__ unsigned short f2bf(float x) {
    union { float f; unsigned int u; } v; v.f = x;
    const unsigned int r = v.u + 0x7fffu + ((v.u >> 16) & 1u);  // RNE
    return (unsigned short)(r >> 16);
}
static __device__ __forceinline__ float bf2f(unsigned short h) {
    union { float f; unsigned int u; } v; v.u = ((unsigned int)h) << 16;
    return v.f;
}

// ---------------------------------------------------------------------------
// Repack conv weight w[F_,CIN,3] fp32 -> bf16 16x16x32 B-fragment order:
//   p[ ((k*(F_/16) + fn)*(CIN/32) + c)*512 + lane*8 + j ]
//     = w[f = fn*16+(lane&15)][d = c*32+(lane>>4)*8+j][k]
// ---------------------------------------------------------------------------
template <int CIN>
static __device__ __forceinline__ void repack_dev(
    int gid, const float* __restrict__ w, unsigned short* __restrict__ p)
{
    constexpr int NC = CIN / 32;
    const int lane = gid & 63;
    int rest = gid >> 6;
    const int c = rest % NC;  rest /= NC;
    const int fn = rest % (F_ / 16);
    const int k  = rest / (F_ / 16);
    const int f = fn * 16 + (lane & 15);
    const int d = c * 32 + (lane >> 4) * 8;
    uint4 o;
    unsigned short* op = (unsigned short*)&o;
#pragma unroll
    for (int j = 0; j < 8; j++)
        op[j] = f2bf(w[((size_t)f * CIN + d + j) * 3 + k]);
    ((uint4*)p)[gid] = o;
}

// ---------------------------------------------------------------------------
// PREP mega-kernel (blockIdx-partitioned, all sections independent):
//   [0,6144)      pitch_add: encb = bf16(enc_out + Conv1d(1->D)(pitch_tgt))
//   [6144,6160)   regulate: cumsum+searchsorted -> idx, dec_mask
//   [6160,6175)   repack proj_w -> pwb
//   [6175,6463)   repack conv0 weights (dur, pitch)
//   [6463,6655)   repack conv1 weights (dur, pitch)
// ---------------------------------------------------------------------------
constexpr int PA_BLK = R_ * D_ / 256;           // 6144
constexpr int RG_BLK = B_;                      // 16
constexpr int PJ_BLK = 15;                      // 3840/256
constexpr int R0_BLK = 3 * F_ * D_ / 8 / 256;   // 144
constexpr int R1_BLK = 3 * F_ * F_ / 8 / 256;   // 96
constexpr int PREP_BLOCKS = PA_BLK + RG_BLK + PJ_BLK + 2 * R0_BLK + 2 * R1_BLK;

__global__ __launch_bounds__(256) void prep_kernel(
    const float* __restrict__ enc_out, const float* __restrict__ pt,
    const float* __restrict__ we, const float* __restrict__ be,
    const int* __restrict__ dur, int* __restrict__ idx_out,
    float* __restrict__ dec_mask,
    const float* __restrict__ projw, unsigned short* __restrict__ pwb,
    const float* __restrict__ c0wd, const float* __restrict__ c0wp,
    unsigned short* __restrict__ p0d, unsigned short* __restrict__ p0p,
    const float* __restrict__ c1wd, const float* __restrict__ c1wp,
    unsigned short* __restrict__ p1d, unsigned short* __restrict__ p1p,
    unsigned short* __restrict__ encb)
{
    __shared__ int cums[T_];
    const int bx = blockIdx.x, tid = threadIdx.x;
    if (bx < PA_BLK) {
        const int gid = bx * 256 + tid;
        const int d  = gid % D_;
        const int bt = gid / D_;
        const int t = bt % T_, b = bt / T_;
        float s = be[d];
#pragma unroll
        for (int k = 0; k < 3; k++) {
            const int t2 = t - 1 + k;
            if (t2 >= 0 && t2 < T_) s = fmaf(we[d * 3 + k], pt[b * T_ + t2], s);
        }
        encb[gid] = f2bf(enc_out[gid] + s);
    } else if (bx < PA_BLK + RG_BLK) {
        const int b = bx - PA_BLK, t = tid;
        cums[t] = (int)rintf((float)dur[b * T_ + t] / PACE_);
        __syncthreads();
        for (int off = 1; off < T_; off <<= 1) {
            int v = cums[t];
            if (t >= off) v += cums[t - off];
            __syncthreads();
            cums[t] = v;
            __syncthreads();
        }
        const int dec_len = min(cums[T_ - 1], M_);
#pragma unroll
        for (int r = 0; r < M_ / T_; r++) {
            const int j = r * T_ + t;
            int lo = 0, hi = T_;
            while (lo < hi) {
                const int mid = (lo + hi) >> 1;
                if (cums[mid] <= j) lo = mid + 1; else hi = mid;
            }
            idx_out[b * M_ + j]  = min(lo, T_ - 1);
            dec_mask[b * M_ + j] = (j < dec_len) ? 1.f : 0.f;
        }
    } else if (bx < PA_BLK + RG_BLK + PJ_BLK) {
        const int gid = (bx - PA_BLK - RG_BLK) * 256 + tid;  // over 3840
        const int lane = gid & 63;
        const int rest = gid >> 6;
        const int nt = rest % 5;
        const int c  = rest / 5;
        const int n = nt * 16 + (lane & 15);
        const int k = c * 32 + (lane >> 4) * 8;
        uint4 o;
        unsigned short* op = (unsigned short*)&o;
#pragma unroll
        for (int j = 0; j < 8; j++)
            op[j] = f2bf(projw[(size_t)n * D_ + k + j]);
        ((uint4*)pwb)[gid] = o;
    } else if (bx < PA_BLK + RG_BLK + PJ_BLK + 2 * R0_BLK) {
        const int i = bx - (PA_BLK + RG_BLK + PJ_BLK);
        const int sel = (i >= R0_BLK) ? 1 : 0;
        const int gid = (i - sel * R0_BLK) * 256 + tid;
        repack_dev<D_>(gid, sel ? c0wp : c0wd, sel ? p0p : p0d);
    } else {
        const int i = bx - (PA_BLK + RG_BLK + PJ_BLK + 2 * R0_BLK);
        const int sel = (i >= R1_BLK) ? 1 : 0;
        const int gid = (i - sel * R1_BLK) * 256 + tid;
        repack_dev<F_>(gid, sel ? c1wp : c1wd, sel ? p1p : p1d);
    }
}

// ---------------------------------------------------------------------------
// Fused conv body: Conv1d(K=3,SAME)+bias+ReLU+LayerNorm[+FC head].
// Block = 32 t-rows x ALL 256 f, 4 waves. Wave w: m-tiles {0,1},
// f-tiles w*4..w*4+3 (each weight fragment loaded once, feeds 2 m-tiles).
// LN over 256 channels: per-lane partial over 4 nf regs -> shfl-xor over the
// 16 lm-lanes -> LDS combine over 4 waves. FC head reuses the same reduction.
// ---------------------------------------------------------------------------
template <int CIN, bool FP32IN, bool FC>
static __device__ __forceinline__ void conv_fused_body(
    const int bx, char* smem,
    const void* __restrict__ in, const float* __restrict__ imask,
    const unsigned short* __restrict__ pw, const float* __restrict__ bias,
    const float* __restrict__ lg, const float* __restrict__ lb,
    unsigned short* __restrict__ out,
    const float* __restrict__ fw, const float* __restrict__ fbp,
    const float* __restrict__ pmask,
    float* __restrict__ pred, float* __restrict__ durpred)
{
    constexpr int LDX = CIN + 8;     // padded row stride (bf16), 16B aligned
    constexpr int NC  = CIN / 32;
    unsigned short* xs = (unsigned short*)smem;
    float* reds = (float*)(smem + 34 * LDX * 2);   // [4 waves][32 rows]
    float* redq = reds + 4 * 32;

    const int r0  = bx * 32;          // 32-row tiles never cross a batch
    const int bb  = r0 >> 8;
    const int tl  = r0 & 255;
    const int tid = threadIdx.x;

    // Stage x rows tl-1 .. tl+32 (34 rows), zero outside batch.
    if constexpr (FP32IN) {
        const float* x = (const float*)in;
        for (int i = tid; i < 34 * (CIN / 8); i += 256) {
            const int row = i / (CIN / 8);
            const int dd  = (i - row * (CIN / 8)) * 8;
            const int t   = tl - 1 + row;
            ushort4 o0 = {0, 0, 0, 0}, o1 = {0, 0, 0, 0};
            if (t >= 0 && t < 256) {
                const float m = imask[bb * 256 + t];
                const float* xr = x + (size_t)(bb * 256 + t) * CIN + dd;
                const float4 v0 = *(const float4*)xr;
                const float4 v1 = *(const float4*)(xr + 4);
                o0.x = f2bf(v0.x * m); o0.y = f2bf(v0.y * m);
                o0.z = f2bf(v0.z * m); o0.w = f2bf(v0.w * m);
                o1.x = f2bf(v1.x * m); o1.y = f2bf(v1.y * m);
                o1.z = f2bf(v1.z * m); o1.w = f2bf(v1.w * m);
            }
            *(ushort4*)(&xs[row * LDX + dd])     = o0;
            *(ushort4*)(&xs[row * LDX + dd + 4]) = o1;
        }
    } else {
        const unsigned short* x = (const unsigned short*)in;
        for (int i = tid; i < 34 * (CIN / 8); i += 256) {
            const int row = i / (CIN / 8);
            const int dd  = (i - row * (CIN / 8)) * 8;
            const int t   = tl - 1 + row;
            uint4 v = make_uint4(0, 0, 0, 0);
            if (t >= 0 && t < 256)
                v = *(const uint4*)(x + (size_t)(bb * 256 + t) * CIN + dd);
            *(uint4*)(&xs[row * LDX + dd]) = v;
        }
    }
    __syncthreads();

    const int w = tid >> 6, l = tid & 63;
    const int q = l >> 4, lm = l & 15;

    f32x4_ acc[2][4];    // [m-tile][nf]
#pragma unroll
    for (int mt = 0; mt < 2; mt++)
#pragma unroll
        for (int nf = 0; nf < 4; nf++)
#pragma unroll
            for (int i = 0; i < 4; i++) acc[mt][nf][i] = 0.f;

    for (int c = 0; c < NC; c++) {
        bf16x8 a[2][3];
#pragma unroll
        for (int mt = 0; mt < 2; mt++)
#pragma unroll
            for (int tap = 0; tap < 3; tap++)
                a[mt][tap] = *(const bf16x8*)(
                    &xs[(mt * 16 + lm + tap) * LDX + c * 32 + q * 8]);
#pragma unroll
        for (int nf = 0; nf < 4; nf++) {
#pragma unroll
            for (int tap = 0; tap < 3; tap++) {
                const bf16x8 bfr = *(const bf16x8*)(
                    pw + ((((size_t)tap * (F_ / 16) + (w * 4 + nf)) * NC + c) << 9) + l * 8);
                acc[0][nf] = __builtin_amdgcn_mfma_f32_16x16x32_bf16(
                    a[0][tap], bfr, acc[0][nf], 0, 0, 0);
                acc[1][nf] = __builtin_amdgcn_mfma_f32_16x16x32_bf16(
                    a[1][tap], bfr, acc[1][nf], 0, 0, 0);
            }
        }
    }

    // bias + ReLU. C/D layout: col=lane&15 (f), row=(lane>>4)*4+reg (m)
    float v[2][4][4];
#pragma unroll
    for (int nf = 0; nf < 4; nf++) {
        const float bs = bias[w * 64 + nf * 16 + lm];
#pragma unroll
        for (int mt = 0; mt < 2; mt++)
#pragma unroll
            for (int r = 0; r < 4; r++)
                v[mt][nf][r] = fmaxf(acc[mt][nf][r] + bs, 0.f);
    }

    // LN partials: per-lane over nf, then over the 16 lm-lanes (bits 0..3)
    float s[2][4], t2[2][4];
#pragma unroll
    for (int mt = 0; mt < 2; mt++)
#pragma unroll
        for (int r = 0; r < 4; r++) {
            s[mt][r]  = v[mt][0][r] + v[mt][1][r] + v[mt][2][r] + v[mt][3][r];
            t2[mt][r] = v[mt][0][r] * v[mt][0][r] + v[mt][1][r] * v[mt][1][r]
                      + v[mt][2][r] * v[mt][2][r] + v[mt][3][r] * v[mt][3][r];
        }
#pragma unroll
    for (int off = 1; off <= 8; off <<= 1)
#pragma unroll
        for (int mt = 0; mt < 2; mt++)
#pragma unroll
            for (int r = 0; r < 4; r++) {
                s[mt][r]  += __shfl_xor(s[mt][r], off);
                t2[mt][r] += __shfl_xor(t2[mt][r], off);
            }
    if (lm == 0) {
#pragma unroll
        for (int mt = 0; mt < 2; mt++)
#pragma unroll
            for (int r = 0; r < 4; r++) {
                reds[w * 32 + mt * 16 + q * 4 + r] = s[mt][r];
                redq[w * 32 + mt * 16 + q * 4 + r] = t2[mt][r];
            }
    }
    __syncthreads();

    float mu[2][4], rsd[2][4];
#pragma unroll
    for (int mt = 0; mt < 2; mt++)
#pragma unroll
        for (int r = 0; r < 4; r++) {
            const int row = mt * 16 + q * 4 + r;
            const float ts = reds[row] + reds[32 + row] + reds[64 + row] + reds[96 + row];
            const float tq = redq[row] + redq[32 + row] + redq[64 + row] + redq[96 + row];
            const float m_ = ts * (1.f / F_);
            mu[mt][r]  = m_;
            rsd[mt][r] = rsqrtf(tq * (1.f / F_) - m_ * m_ + 1e-5f);
        }

    if constexpr (!FC) {
#pragma unroll
        for (int nf = 0; nf < 4; nf++) {
            const int f = w * 64 + nf * 16 + lm;
            const float gg = lg[f], bb2 = lb[f];
#pragma unroll
            for (int mt = 0; mt < 2; mt++)
#pragma unroll
                for (int r = 0; r < 4; r++) {
                    const float o = (v[mt][nf][r] - mu[mt][r]) * rsd[mt][r] * gg + bb2;
                    out[(size_t)(r0 + mt * 16 + q * 4 + r) * F_ + f] = f2bf(o);
                }
        }
    } else {
        // FC head: pred[row] = (dot(LN(v), fw) + fb) * mask[row]
        float fcp[2][4];
#pragma unroll
        for (int mt = 0; mt < 2; mt++)
#pragma unroll
            for (int r = 0; r < 4; r++) fcp[mt][r] = 0.f;
#pragma unroll
        for (int nf = 0; nf < 4; nf++) {
            const int f = w * 64 + nf * 16 + lm;
            const float gg = lg[f], bb2 = lb[f], wv = fw[f];
#pragma unroll
            for (int mt = 0; mt < 2; mt++)
#pragma unroll
                for (int r = 0; r < 4; r++)
                    fcp[mt][r] += ((v[mt][nf][r] - mu[mt][r]) * rsd[mt][r] * gg + bb2) * wv;
        }
#pragma unroll
        for (int off = 1; off <= 8; off <<= 1)
#pragma unroll
            for (int mt = 0; mt < 2; mt++)
#pragma unroll
                for (int r = 0; r < 4; r++)
                    fcp[mt][r] += __shfl_xor(fcp[mt][r], off);
        __syncthreads();   // reds fully read above before reuse
        if (lm == 0) {
#pragma unroll
            for (int mt = 0; mt < 2; mt++)
#pragma unroll
                for (int r = 0; r < 4; r++)
                    reds[w * 32 + mt * 16 + q * 4 + r] = fcp[mt][r];
        }
        __syncthreads();
        if (tid < 32) {
            const float tot = reds[tid] + reds[32 + tid] + reds[64 + tid]
                            + reds[96 + tid] + fbp[0];
            const int row = r0 + tid;
            const float p = tot * pmask[row];
            pred[row] = p;
            if (durpred) durpred[row] = fminf(fmaxf(expf(p) - 1.f, 0.f), MAXDUR_);
        }
    }
}

// ---------------------------------------------------------------------------
// Launch 2: conv0+ReLU+LN0 (dur+pitch, blocks 0..255) ∥ mel gather-GEMM
// (blocks 256..767). Mutually independent; conv is MFMA-bound, mel is
// memory-bound -> good co-residency.
// ---------------------------------------------------------------------------
constexpr int SMEM_A = 34 * (D_ + 8) * 2 + 2 * 4 * 32 * 4;   // 27680 B

__global__ __launch_bounds__(256) void convln_mel_kernel(
    const float* __restrict__ enc_out, const float* __restrict__ enc_mask,
    const unsigned short* __restrict__ p0d, const unsigned short* __restrict__ p0p,
    const float* __restrict__ cb_d, const float* __restrict__ cb_p,
    const float* __restrict__ g_d, const float* __restrict__ be_d,
    const float* __restrict__ g_p, const float* __restrict__ be_p,
    unsigned short* __restrict__ h_d, unsigned short* __restrict__ h_p,
    const unsigned short* __restrict__ encb, const int* __restrict__ idx,
    const float* __restrict__ dmask, const unsigned short* __restrict__ pwb,
    const float* __restrict__ pb, float* __restrict__ mel)
{
    __shared__ __align__(16) char smem[SMEM_A];
    const int bxx = blockIdx.x;
    if (bxx < 256) {
        const int z = bxx >> 7;
        conv_fused_body<D_, true, false>(bxx & 127, smem,
            enc_out, enc_mask,
            z ? p0p : p0d, z ? cb_p : cb_d,
            z ? g_p : g_d, z ? be_p : be_d,
            z ? h_p : h_d,
            nullptr, nullptr, nullptr, nullptr, nullptr);
        return;
    }
    // ---- mel branch: mel[b,j,n] = dmask*dot(encb[b,idx[b,j],:], proj[n,:])+pb
    int* ids = (int*)smem;
    const int i  = bxx - 256;
    const int b  = i >> 5;
    const int j0 = (i & 31) * 64;
    const int tid = threadIdx.x;
    if (tid < 64) ids[tid] = idx[b * M_ + j0 + tid];
    __syncthreads();

    const int w = tid >> 6, l = tid & 63;
    const int q = l >> 4, lm = l & 15;
    const int row = ids[w * 16 + lm];
    const unsigned short* ap = encb + ((size_t)(b * 256 + row)) * D_ + q * 8;

    f32x4_ acc[5];
#pragma unroll
    for (int nt = 0; nt < 5; nt++)
#pragma unroll
        for (int k = 0; k < 4; k++) acc[nt][k] = 0.f;

    for (int c = 0; c < D_ / 32; c++) {
        const bf16x8 a = *(const bf16x8*)(ap + c * 32);
#pragma unroll
        for (int nt = 0; nt < 5; nt++) {
            const bf16x8 bv = *(const bf16x8*)(pwb + (((size_t)c * 5 + nt) << 9) + l * 8);
            acc[nt] = __builtin_amdgcn_mfma_f32_16x16x32_bf16(a, bv, acc[nt], 0, 0, 0);
        }
    }

    float msk[4];
#pragma unroll
    for (int r = 0; r < 4; r++)
        msk[r] = dmask[b * M_ + j0 + w * 16 + q * 4 + r];
#pragma unroll
    for (int nt = 0; nt < 5; nt++) {
        const int n = nt * 16 + lm;
        const float bb = pb[n];
#pragma unroll
        for (int r = 0; r < 4; r++) {
            const int j = j0 + w * 16 + q * 4 + r;
            mel[((size_t)b * M_ + j) * NMEL_ + n] = msk[r] * acc[nt][r] + bb;
        }
    }
}

// ---------------------------------------------------------------------------
// Launch 3: conv1+ReLU+LN1+FC (+mask, +dur_pred). LN1 output never hits HBM.
// ---------------------------------------------------------------------------
constexpr int SMEM_B = 34 * (F_ + 8) * 2 + 2 * 4 * 32 * 4;   // 18976 B

__global__ __launch_bounds__(256) void conv1fc_kernel(
    const unsigned short* __restrict__ h_d, const unsigned short* __restrict__ h_p,
    const unsigned short* __restrict__ p1d, const unsigned short* __restrict__ p1p,
    const float* __restrict__ cb_d, const float* __restrict__ cb_p,
    const float* __restrict__ g_d, const float* __restrict__ be_d,
    const float* __restrict__ g_p, const float* __restrict__ be_p,
    const float* __restrict__ fw_d, const float* __restrict__ fw_p,
    const float* __restrict__ fb_d, const float* __restrict__ fb_p,
    const float* __restrict__ pmask,
    float* __restrict__ log_dur, float* __restrict__ pitch_prd,
    float* __restrict__ durpred)
{
    __shared__ __align__(16) char smem[SMEM_B];
    const int z = blockIdx.y;
    conv_fused_body<F_, false, true>(blockIdx.x, smem,
        z ? (const void*)h_p : (const void*)h_d, nullptr,
        z ? p1p : p1d, z ? cb_p : cb_d,
        z ? g_p : g_d, z ? be_p : be_d,
        nullptr,
        z ? fw_p : fw_d, z ? fb_p : fb_d, pmask,
        z ? pitch_prd : log_dur, z ? nullptr : durpred);
}

// ---------------------------------------------------------------------------
extern "C" void kernel_launch(void* const* d_in, const int* in_sizes, int n_in,
                              void* d_out, int out_size, void* d_ws, size_t ws_size,
                              hipStream_t stream)
{
    const float* enc_out   = (const float*)d_in[0];
    const float* enc_mask  = (const float*)d_in[1];
    const float* pitch_tgt = (const float*)d_in[2];
    const int*   durations = (const int*)d_in[3];

    const float* dur_c0_w = (const float*)d_in[4];
    const float* dur_c0_b = (const float*)d_in[5];
    const float* dur_n0_g = (const float*)d_in[6];
    const float* dur_n0_b = (const float*)d_in[7];
    const float* dur_c1_w = (const float*)d_in[8];
    const float* dur_c1_b = (const float*)d_in[9];
    const float* dur_n1_g = (const float*)d_in[10];
    const float* dur_n1_b = (const float*)d_in[11];
    const float* dur_fc_w = (const float*)d_in[12];
    const float* dur_fc_b = (const float*)d_in[13];

    const float* pit_c0_w = (const float*)d_in[14];
    const float* pit_c0_b = (const float*)d_in[15];
    const float* pit_n0_g = (const float*)d_in[16];
    const float* pit_n0_b = (const float*)d_in[17];
    const float* pit_c1_w = (const float*)d_in[18];
    const float* pit_c1_b = (const float*)d_in[19];
    const float* pit_n1_g = (const float*)d_in[20];
    const float* pit_n1_b = (const float*)d_in[21];
    const float* pit_fc_w = (const float*)d_in[22];
    const float* pit_fc_b = (const float*)d_in[23];

    const float* pemb_w = (const float*)d_in[24];
    const float* pemb_b = (const float*)d_in[25];
    const float* proj_w = (const float*)d_in[26];
    const float* proj_b = (const float*)d_in[27];

    // Output slices (flat, in return order), all fp32.
    float* out       = (float*)d_out;
    float* mel_out   = out;                                   // [B,M,NMEL]
    float* dec_mask  = mel_out + (size_t)B_ * M_ * NMEL_;     // [B,M,1]
    float* dur_pred  = dec_mask + (size_t)B_ * M_;            // [B,T]
    float* log_dur   = dur_pred + (size_t)B_ * T_;            // [B,T]
    float* pitch_prd = log_dur + (size_t)B_ * T_;             // [B,T]

    // Workspace layout (~9.5 MiB)
    char* wp = (char*)d_ws;
    unsigned short* h_d  = (unsigned short*)wp; wp += (size_t)R_ * F_ * 2;      // LN0 out dur
    unsigned short* h_p  = (unsigned short*)wp; wp += (size_t)R_ * F_ * 2;      // LN0 out pitch
    unsigned short* p0d  = (unsigned short*)wp; wp += (size_t)3 * F_ * D_ * 2;  // conv0 w dur
    unsigned short* p0p  = (unsigned short*)wp; wp += (size_t)3 * F_ * D_ * 2;  // conv0 w pitch
    unsigned short* p1d  = (unsigned short*)wp; wp += (size_t)3 * F_ * F_ * 2;  // conv1 w dur
    unsigned short* p1p  = (unsigned short*)wp; wp += (size_t)3 * F_ * F_ * 2;  // conv1 w pitch
    unsigned short* encb = (unsigned short*)wp; wp += (size_t)R_ * D_ * 2;      // enc+pitch bf16
    unsigned short* pwb  = (unsigned short*)wp; wp += (size_t)5 * 12 * 512 * 2; // proj packed
    int*            idx  = (int*)wp;                                            // [B,M]

    const dim3 blk(256);

    // 1: all independent prep (pitch_add, regulate, 3x weight repack)
    prep_kernel<<<PREP_BLOCKS, blk, 0, stream>>>(
        enc_out, pitch_tgt, pemb_w, pemb_b,
        durations, idx, dec_mask,
        proj_w, pwb,
        dur_c0_w, pit_c0_w, p0d, p0p,
        dur_c1_w, pit_c1_w, p1d, p1p,
        encb);

    // 2: conv0+ReLU+LN0 (both predictors) ∥ mel gather-GEMM
    convln_mel_kernel<<<256 + (M_ / 64) * B_, blk, 0, stream>>>(
        enc_out, enc_mask, p0d, p0p, dur_c0_b, pit_c0_b,
        dur_n0_g, dur_n0_b, pit_n0_g, pit_n0_b,
        h_d, h_p, encb, idx, dec_mask, pwb, proj_b, mel_out);

    // 3: conv1+ReLU+LN1+FC heads
    conv1fc_kernel<<<dim3(R_ / 32, 2), blk, 0, stream>>>(
        h_d, h_p, p1d, p1p, dur_c1_b, pit_c1_b,
        dur_n1_g, dur_n1_b, pit_n1_g, pit_n1_b,
        dur_fc_w, pit_fc_w, dur_fc_b, pit_fc_b, enc_mask,
        log_dur, pitch_prd, dur_pred);
}